// Round 2
// baseline (497.542 us; speedup 1.0000x reference)
//
#include <hip/hip_runtime.h>

// NaturalVariation: out = x + softmax(x@W_sel + b_sel)@patterns + EMA(0.05*noise)
// B=4, T=8192, H=1024, P=8. fp32 in/out. HBM-bound: floor = 384 MB ~ 61 us.
//
// EMA truncation: 0.9^64 = 1.18e-3 -> worst-case dropped tail
// <= 0.05*|noise|max*0.9^65/0.1 ~ 3.5e-4 << 0.11 threshold. So chunks of
// T are independent given a 64-step warm-up -> no serial scan, no carries.

#define T_LEN 8192
#define H_DIM 1024
#define B_DIM 4
#define NPAT 8
#define CHUNK 128            // tokens per kB block
#define WARM 64              // EMA warm-up steps
#define NCHUNK (T_LEN / CHUNK)   // 64 chunks per batch row

static_assert(WARM < CHUNK, "warm-up must stay within previous chunk");

// ---------------- Kernel A: per-token softmax weights --------------------
// One wave per token. Lane l covers h = r*256 + l*4 .. +3 for r=0..3.
__global__ __launch_bounds__(256) void kA_weights(
    const float* __restrict__ x, const float* __restrict__ Wsel,
    const float* __restrict__ bsel, float* __restrict__ wts)
{
    const int wave = threadIdx.x >> 6;
    const int lane = threadIdx.x & 63;
    const int tok  = blockIdx.x * 4 + wave;        // 0 .. B*T-1
    const float* xrow = x + (size_t)tok * H_DIM;

    float acc[NPAT];
#pragma unroll
    for (int p = 0; p < NPAT; ++p) acc[p] = 0.0f;

#pragma unroll
    for (int r = 0; r < 4; ++r) {
        const int h0 = r * 256 + lane * 4;
        float4 xv = *(const float4*)(xrow + h0);
        const float* wr = Wsel + (size_t)h0 * NPAT;   // 4 rows x 8 = 32 floats
        float wl[32];
#pragma unroll
        for (int j = 0; j < 8; ++j)
            *(float4*)(wl + 4 * j) = *(const float4*)(wr + 4 * j);
        float xs[4] = {xv.x, xv.y, xv.z, xv.w};
#pragma unroll
        for (int row = 0; row < 4; ++row)
#pragma unroll
            for (int p = 0; p < NPAT; ++p)
                acc[p] = fmaf(xs[row], wl[row * 8 + p], acc[p]);
    }

    // full-wave butterfly reduction of 8 partials
#pragma unroll
    for (int off = 1; off < 64; off <<= 1)
#pragma unroll
        for (int p = 0; p < NPAT; ++p)
            acc[p] += __shfl_xor(acc[p], off, 64);

#pragma unroll
    for (int p = 0; p < NPAT; ++p) acc[p] += bsel[p];   // TEMPERATURE == 1.0

    // softmax (redundant on all lanes; lane 0 stores)
    float m = acc[0];
#pragma unroll
    for (int p = 1; p < NPAT; ++p) m = fmaxf(m, acc[p]);
    float e[NPAT], sum = 0.0f;
#pragma unroll
    for (int p = 0; p < NPAT; ++p) { e[p] = __expf(acc[p] - m); sum += e[p]; }
    const float inv = 1.0f / sum;

    if (lane == 0) {
        float* wp = wts + (size_t)tok * NPAT;
        *(float4*)(wp + 0) = make_float4(e[0] * inv, e[1] * inv, e[2] * inv, e[3] * inv);
        *(float4*)(wp + 4) = make_float4(e[4] * inv, e[5] * inv, e[6] * inv, e[7] * inv);
    }
}

// ---------------- Kernel B: fused variation + EMA + add ------------------
// Block = (b, chunk). 256 threads, thread tid covers h = tid*4 .. +3.
__global__ __launch_bounds__(256) void kB_fused(
    const float* __restrict__ x, const float* __restrict__ noise,
    const float* __restrict__ patterns, const float* __restrict__ wts,
    float* __restrict__ out)
{
    __shared__ float wsm[CHUNK * NPAT];   // 4 KB: this chunk's token weights

    const int cid = blockIdx.x;                 // 0 .. B*NCHUNK-1
    const int b = cid / NCHUNK;
    const int c = cid % NCHUNK;
    const int t0 = c * CHUNK;
    const size_t tokbase = (size_t)b * T_LEN + t0;
    const int tid = threadIdx.x;

    // stage weights for CHUNK tokens: 128*8 = 1024 floats, 4 per thread
    *(float4*)(wsm + tid * 4) = *(const float4*)(wts + tokbase * NPAT + tid * 4);
    __syncthreads();

    const int h0 = tid * 4;
    float4 pat[NPAT];
#pragma unroll
    for (int p = 0; p < NPAT; ++p)
        pat[p] = *(const float4*)(patterns + p * H_DIM + h0);

    // EMA warm-up: 64 truncated-history steps (chunk 0 is exact from t=0)
    float4 s = make_float4(0.f, 0.f, 0.f, 0.f);
    const int nw = (c == 0) ? 0 : WARM;
    const float* nptr = noise + (tokbase - nw) * (size_t)H_DIM + h0;
#pragma unroll 4
    for (int i = 0; i < nw; ++i) {
        float4 nv = *(const float4*)nptr;
        s.x = fmaf(0.9f, s.x, 0.005f * nv.x);
        s.y = fmaf(0.9f, s.y, 0.005f * nv.y);
        s.z = fmaf(0.9f, s.z, 0.005f * nv.z);
        s.w = fmaf(0.9f, s.w, 0.005f * nv.w);
        nptr += H_DIM;
    }

    const float* xptr = x + tokbase * H_DIM + h0;
    float*       optr = out + tokbase * H_DIM + h0;
#pragma unroll 4
    for (int i = 0; i < CHUNK; ++i) {
        float4 nv = *(const float4*)nptr;
        float4 xv = *(const float4*)xptr;
        s.x = fmaf(0.9f, s.x, 0.005f * nv.x);
        s.y = fmaf(0.9f, s.y, 0.005f * nv.y);
        s.z = fmaf(0.9f, s.z, 0.005f * nv.z);
        s.w = fmaf(0.9f, s.w, 0.005f * nv.w);

        float4 wA = *(const float4*)(wsm + i * NPAT);
        float4 wB = *(const float4*)(wsm + i * NPAT + 4);
        float w[8] = {wA.x, wA.y, wA.z, wA.w, wB.x, wB.y, wB.z, wB.w};
        float4 v = make_float4(0.f, 0.f, 0.f, 0.f);
#pragma unroll
        for (int p = 0; p < NPAT; ++p) {
            v.x = fmaf(w[p], pat[p].x, v.x);
            v.y = fmaf(w[p], pat[p].y, v.y);
            v.z = fmaf(w[p], pat[p].z, v.z);
            v.w = fmaf(w[p], pat[p].w, v.w);
        }
        float4 o = make_float4(xv.x + v.x + s.x, xv.y + v.y + s.y,
                               xv.z + v.z + s.z, xv.w + v.w + s.w);
        *(float4*)optr = o;
        nptr += H_DIM; xptr += H_DIM; optr += H_DIM;
    }
}

extern "C" void kernel_launch(void* const* d_in, const int* in_sizes, int n_in,
                              void* d_out, int out_size, void* d_ws, size_t ws_size,
                              hipStream_t stream) {
    const float* x        = (const float*)d_in[0];  // [B,T,H]
    const float* Wsel     = (const float*)d_in[1];  // [H,8]
    const float* bsel     = (const float*)d_in[2];  // [8]
    const float* patterns = (const float*)d_in[3];  // [8,H]
    const float* noise    = (const float*)d_in[4];  // [B,T,H]
    float* out = (float*)d_out;
    float* wts = (float*)d_ws;                      // [B,T,8] = 1 MB scratch

    const int n_tok = B_DIM * T_LEN;                // 32768
    kA_weights<<<n_tok / 4, 256, 0, stream>>>(x, Wsel, bsel, wts);
    kB_fused<<<B_DIM * NCHUNK, 256, 0, stream>>>(x, noise, patterns, wts, out);
}